// Round 15
// baseline (211.306 us; speedup 1.0000x reference)
//
#include <hip/hip_runtime.h>
#include <hip/hip_bf16.h>
#include <stdint.h>

typedef __bf16 bf16x8 __attribute__((ext_vector_type(8)));
typedef short short8v __attribute__((ext_vector_type(8)));
typedef float f32x4 __attribute__((ext_vector_type(4)));

#define B_     128
#define T_     448
#define NS     384
#define NH     6
#define HD     64
#define VOCAB_ 10000
#define NOUT   22020096   // B_*T_*NS

// ws layout (ushort element offsets). Tables are bf16.
// qtab: (emb@Wq^T + bq) * scale * log2(e)  (pre-scaled for exp2 softmax)
// ktab: (emb@Wk^T) * scale        (pre-scaled; gather multiplies by 1/scale)
// vtab: (emb@Wv^T + bv)           (unscaled)
// ctx : attention output, bf16 [M][384]
#define OFF_WQ   0
#define OFF_WK   147456
#define OFF_WV   294912
#define OFF_WO   442368
#define OFF_QTAB 589824
#define OFF_KTAB 4429824
#define OFF_VTAB 8269824
#define OFF_CTX  12109824
// end: 34129920 ushorts = 68.3 MB

#define NATT (B_ * NH * 7)        // 5376 attention blocks
#define NGAT 10752                // gather blocks (2752512 chunks / 256)
#define NFUSE (NATT * 3)          // 16128 fused-grid blocks (div by 8)

__device__ __forceinline__ unsigned short f2bf(float f) {
    // native f32->bf16 convert (RTNE on gfx950)
    union { __bf16 h; unsigned short u; } v;
    v.h = (__bf16)f;
    return v.u;
}
__device__ __forceinline__ float bf2f(unsigned short u) {
    union { uint32_t u; float f; } v; v.u = (uint32_t)u << 16;
    return v.f;
}

// ---------------- kernel 0: f32 -> bf16 weights only ----------------------
__global__ __launch_bounds__(256) void k_prep(
    const float* __restrict__ Wq, const float* __restrict__ Wk,
    const float* __restrict__ Wv, const float* __restrict__ Wo,
    unsigned short* __restrict__ ws)
{
    const float* srcs[4] = {Wq, Wk, Wv, Wo};
    const int seg = blockIdx.y;
    int i = (blockIdx.x * 256 + threadIdx.x) * 4;
    if (i >= 147456) return;
    float4 v = *(const float4*)(srcs[seg] + i);
    ushort4 o;
    o.x = f2bf(v.x); o.y = f2bf(v.y); o.z = f2bf(v.z); o.w = f2bf(v.w);
    *(ushort4*)(ws + seg * 147456 + i) = o;
}

// ---------------- kernel 1: vocab projection tables -----------------------
// grid (313, 3): 32 vocab rows per block; y: 0=q,1=k,2=v.
__global__ __launch_bounds__(256) void k_table(
    const float* __restrict__ emb, const unsigned short* __restrict__ ws,
    const float* __restrict__ bq, const float* __restrict__ bv,
    unsigned short* __restrict__ wso)
{
    const int p  = blockIdx.y;
    const int v0 = blockIdx.x * 32;
    const int tid = threadIdx.x;
    const int lane = tid & 63, wv = tid >> 6;

    __shared__ __align__(16) unsigned short sA[32][392];

    {   // stage 32x384 emb rows, f32 -> bf16
        int r = tid >> 3;
        int srow = min(v0 + r, VOCAB_ - 1);
        const float* src = emb + (size_t)srow * NS + (tid & 7) * 48;
        unsigned short* dst = &sA[r][(tid & 7) * 48];
        #pragma unroll
        for (int j = 0; j < 6; ++j) {
            float4 a0 = *(const float4*)(src + j * 8);
            float4 a1 = *(const float4*)(src + j * 8 + 4);
            ushort4 o0, o1;
            o0.x = f2bf(a0.x); o0.y = f2bf(a0.y); o0.z = f2bf(a0.z); o0.w = f2bf(a0.w);
            o1.x = f2bf(a1.x); o1.y = f2bf(a1.y); o1.z = f2bf(a1.z); o1.w = f2bf(a1.w);
            *(ushort4*)(dst + j * 8) = o0;
            *(ushort4*)(dst + j * 8 + 4) = o1;
        }
    }
    __syncthreads();

    f32x4 acc[2][6];
    #pragma unroll
    for (int i = 0; i < 2; ++i)
        #pragma unroll
        for (int j = 0; j < 6; ++j) acc[i][j] = (f32x4){0.f, 0.f, 0.f, 0.f};

    const int colA = lane & 15;
    const int kb = (lane >> 4) * 8;
    const unsigned short* wlane =
        ws + (size_t)p * 147456 + (size_t)(wv * 96 + colA) * NS + kb;

    #pragma unroll 2
    for (int kc = 0; kc < 12; ++kc) {
        bf16x8 a[2], b[6];
        #pragma unroll
        for (int mf = 0; mf < 2; ++mf)
            a[mf] = *(const bf16x8*)&sA[mf * 16 + colA][kc * 32 + kb];
        #pragma unroll
        for (int nf = 0; nf < 6; ++nf)
            b[nf] = *(const bf16x8*)(wlane + (size_t)(nf * 16) * NS + kc * 32);
        #pragma unroll
        for (int mf = 0; mf < 2; ++mf)
            #pragma unroll
            for (int nf = 0; nf < 6; ++nf)
                acc[mf][nf] = __builtin_amdgcn_mfma_f32_16x16x32_bf16(
                    a[mf], b[nf], acc[mf][nf], 0, 0, 0);
    }

    const int r0 = (lane >> 4) * 4;
    const float scale = 0.35355339059327373f;            // 64^-0.25
    const float qscale = 0.35355339059327373f * 1.4426950408889634f; // * log2(e)

    if (p == 0) {
        unsigned short* qt_ = wso + OFF_QTAB;
        #pragma unroll
        for (int nf = 0; nf < 6; ++nf) {
            int n = wv * 96 + nf * 16 + colA;
            float bias = bq[n];
            #pragma unroll
            for (int mf = 0; mf < 2; ++mf)
                #pragma unroll
                for (int r = 0; r < 4; ++r) {
                    int row = v0 + mf * 16 + r0 + r;
                    if (row < VOCAB_)
                        qt_[(size_t)row * NS + n] = f2bf((acc[mf][nf][r] + bias) * qscale);
                }
        }
    } else if (p == 1) {
        unsigned short* kt_ = wso + OFF_KTAB;
        #pragma unroll
        for (int nf = 0; nf < 6; ++nf) {
            int n = wv * 96 + nf * 16 + colA;
            #pragma unroll
            for (int mf = 0; mf < 2; ++mf)
                #pragma unroll
                for (int r = 0; r < 4; ++r) {
                    int row = v0 + mf * 16 + r0 + r;
                    if (row < VOCAB_)
                        kt_[(size_t)row * NS + n] = f2bf(acc[mf][nf][r] * scale);
                }
        }
    } else {
        unsigned short* vt_ = wso + OFF_VTAB;
        #pragma unroll
        for (int nf = 0; nf < 6; ++nf) {
            int n = wv * 96 + nf * 16 + colA;
            float bias = bv[n];
            #pragma unroll
            for (int mf = 0; mf < 2; ++mf)
                #pragma unroll
                for (int r = 0; r < 4; ++r) {
                    int row = v0 + mf * 16 + r0 + r;
                    if (row < VOCAB_)
                        vt_[(size_t)row * NS + n] = f2bf(acc[mf][nf][r] + bias);
                }
        }
    }
}

// ---------------- kernel 2: fused causal flash attention + k/v gather -----
// Round-6 structure (best measured: 192.9 us). Single change: 2-DEEP register
// prefetch. Tile kv's table loads issue at iter kv-2 (prologue covers tiles
// 0,1), so ~2 tiles of MFMA+exp compute (~1000+ cy) cover the ~900 cy random
// L3/HBM table-read latency that 1-deep (~500 cy window) could not. LDS stays
// single-buffered 27.6 KB (round-13 showed dbuf's LDS growth costs blocks/CU).
// +~24 VGPR stays within the same 128<v<=170 occupancy band (3 waves/SIMD).
__global__ __launch_bounds__(256) void k_attn_gather(
    const int* __restrict__ x, const unsigned short* __restrict__ ws,
    unsigned short* __restrict__ ctxb,
    float* __restrict__ out_k, float* __restrict__ out_v)
{
    const int swz = (blockIdx.x & 7) * (NFUSE / 8) + (blockIdx.x >> 3);
    const int r3 = swz % 3;
    const int q3 = swz / 3;

    if (r3 != 0) {
        // ---------------- gather path (2 of every 3 blocks) ----------------
        int i = (2 * q3 + (r3 - 1)) * 256 + threadIdx.x;  // chunk id < 2752512
        int row = i / 48;
        int c = (i - row * 48) * 8;
        int tok = x[row];
        const unsigned short* ks = ws + OFF_KTAB + (size_t)tok * NS + c;
        const unsigned short* vs = ws + OFF_VTAB + (size_t)tok * NS + c;
        ushort4 k0 = *(const ushort4*)ks;
        ushort4 k1 = *(const ushort4*)(ks + 4);
        ushort4 v0 = *(const ushort4*)vs;
        ushort4 v1 = *(const ushort4*)(vs + 4);
        const float inv = 2.8284271247461903f;   // 1/scale: ktab is pre-scaled
        float4 fk0 = {bf2f(k0.x) * inv, bf2f(k0.y) * inv, bf2f(k0.z) * inv, bf2f(k0.w) * inv};
        float4 fk1 = {bf2f(k1.x) * inv, bf2f(k1.y) * inv, bf2f(k1.z) * inv, bf2f(k1.w) * inv};
        float4 fv0 = {bf2f(v0.x), bf2f(v0.y), bf2f(v0.z), bf2f(v0.w)};
        float4 fv1 = {bf2f(v1.x), bf2f(v1.y), bf2f(v1.z), bf2f(v1.w)};
        size_t base = (size_t)row * NS + c;
        *(float4*)(out_k + base)     = fk0;
        *(float4*)(out_k + base + 4) = fk1;
        *(float4*)(out_v + base)     = fv0;
        *(float4*)(out_v + base + 4) = fv1;
        return;
    }

    // ---------------- attention path ----------------
    const int bid = q3;
    const int qt = bid % 7;
    const int h  = (bid / 7) % NH;
    const int b  = bid / (7 * NH);
    const int tid = threadIdx.x;
    const int lane = tid & 63, wv = tid >> 6;

    __shared__ __align__(16) unsigned short sK[64][72];
    __shared__ __align__(16) unsigned short sVT[64][72];
    __shared__ __align__(16) unsigned short sP[4][16][72];

    const int* xb = x + (size_t)b * T_;
    const unsigned short* qtab = ws + OFF_QTAB;
    const unsigned short* ktab = ws + OFF_KTAB;
    const unsigned short* vtab = ws + OFF_VTAB;

    const int qrow = qt * 64 + wv * 16 + (lane & 15);
    const int qtok = xb[qrow];
    const unsigned short* qbase =
        qtab + (size_t)qtok * NS + h * HD + (lane >> 4) * 8;
    bf16x8 qf0 = *(const bf16x8*)qbase;
    bf16x8 qf1 = *(const bf16x8*)(qbase + 32);

    f32x4 o[4];
    #pragma unroll
    for (int nf = 0; nf < 4; ++nf) o[nf] = (f32x4){0.f, 0.f, 0.f, 0.f};
    float lsum[4] = {0.f, 0.f, 0.f, 0.f};

    const int tk = tid >> 2;          // K-staging: token 0..63
    const int cc = (tid & 3) * 16;    // K-staging: d chunk
    const int vd = tid & 63;          // V-staging: d row
    const int vg = tid >> 6;          // V-staging: token group (16 tokens)

    // 2-deep prefetch: set A holds even tiles, set B holds odd tiles.
    short8v ka0, ka1, kb0r, kb1r;
    unsigned short tva[16], tvb[16];
    {   // prologue: tile 0 -> set A
        int tkn = xb[tk];
        const unsigned short* kset = ktab + (size_t)tkn * NS + h * HD + cc;
        ka0 = *(const short8v*)kset;
        ka1 = *(const short8v*)(kset + 8);
        #pragma unroll
        for (int j = 0; j < 16; ++j) {
            int t = xb[vg * 16 + j];
            tva[j] = vtab[(size_t)t * NS + h * HD + vd];
        }
    }
    if (qt >= 1) {   // prologue: tile 1 -> set B
        int tkn = xb[64 + tk];
        const unsigned short* kset = ktab + (size_t)tkn * NS + h * HD + cc;
        kb0r = *(const short8v*)kset;
        kb1r = *(const short8v*)(kset + 8);
        #pragma unroll
        for (int j = 0; j < 16; ++j) {
            int t = xb[64 + vg * 16 + j];
            tvb[j] = vtab[(size_t)t * NS + h * HD + vd];
        }
    }

    for (int kv = 0; kv <= qt; ++kv) {
        const bool even = (kv & 1) == 0;
        __syncthreads();
        // write the prefetched tile (issued at iter kv-2: two full tiles of
        // compute have elapsed -> vmcnt wait here is satisfied) into LDS
        if (even) {
            *(short8v*)&sK[tk][cc]           = ka0;
            *(short8v*)&sK[tk][cc + 8]       = ka1;
            *(short8v*)&sVT[vd][vg * 16]     = *(const short8v*)&tva[0];
            *(short8v*)&sVT[vd][vg * 16 + 8] = *(const short8v*)&tva[8];
        } else {
            *(short8v*)&sK[tk][cc]           = kb0r;
            *(short8v*)&sK[tk][cc + 8]       = kb1r;
            *(short8v*)&sVT[vd][vg * 16]     = *(const short8v*)&tvb[0];
            *(short8v*)&sVT[vd][vg * 16 + 8] = *(const short8v*)&tvb[8];
        }
        __syncthreads();

        // refill the just-freed register set with tile kv+2
        if (kv + 2 <= qt) {
            int base = (kv + 2) * 64;
            int tkn = xb[base + tk];
            const unsigned short* kset = ktab + (size_t)tkn * NS + h * HD + cc;
            if (even) {
                ka0 = *(const short8v*)kset;
                ka1 = *(const short8v*)(kset + 8);
                #pragma unroll
                for (int j = 0; j < 16; ++j) {
                    int t = xb[base + vg * 16 + j];
                    tva[j] = vtab[(size_t)t * NS + h * HD + vd];
                }
            } else {
                kb0r = *(const short8v*)kset;
                kb1r = *(const short8v*)(kset + 8);
                #pragma unroll
                for (int j = 0; j < 16; ++j) {
                    int t = xb[base + vg * 16 + j];
                    tvb[j] = vtab[(size_t)t * NS + h * HD + vd];
                }
            }
        }

        // S = Q K^T  (16 q-rows x 64 kv-cols per wave); logits already *log2e
        f32x4 s[4];
        #pragma unroll
        for (int nf = 0; nf < 4; ++nf) s[nf] = (f32x4){0.f, 0.f, 0.f, 0.f};
        #pragma unroll
        for (int nf = 0; nf < 4; ++nf) {
            bf16x8 kf0 = *(const bf16x8*)&sK[nf * 16 + (lane & 15)][(lane >> 4) * 8];
            s[nf] = __builtin_amdgcn_mfma_f32_16x16x32_bf16(qf0, kf0, s[nf], 0, 0, 0);
            bf16x8 kf1 = *(const bf16x8*)&sK[nf * 16 + (lane & 15)][32 + (lane >> 4) * 8];
            s[nf] = __builtin_amdgcn_mfma_f32_16x16x32_bf16(qf1, kf1, s[nf], 0, 0, 0);
        }

        // no-max softmax: p = exp2(s); only diagonal tile needs the mask.
        // Tile-local row of this lane's r-th acc row is wv*16 + (lane>>4)*4 + r.
        if (kv == qt) {
            const int rloc = wv * 16 + (lane >> 4) * 4;   // tile-local row base
            const int cloc = lane & 15;
            #pragma unroll
            for (int nf = 0; nf < 4; ++nf)
                #pragma unroll
                for (int r = 0; r < 4; ++r) {
                    float sv = (cloc + nf * 16 > rloc + r) ? -1e30f : s[nf][r];
                    float p = exp2f(sv);
                    s[nf][r] = p;
                    lsum[r] += p;
                }
        } else {
            #pragma unroll
            for (int nf = 0; nf < 4; ++nf)
                #pragma unroll
                for (int r = 0; r < 4; ++r) {
                    float p = exp2f(s[nf][r]);
                    s[nf][r] = p;
                    lsum[r] += p;
                }
        }

        // P (D-layout) -> per-wave LDS -> A-frag layout
        #pragma unroll
        for (int nf = 0; nf < 4; ++nf)
            #pragma unroll
            for (int r = 0; r < 4; ++r)
                sP[wv][(lane >> 4) * 4 + r][nf * 16 + (lane & 15)] = f2bf(s[nf][r]);
        asm volatile("s_waitcnt lgkmcnt(0)" ::: "memory");

        bf16x8 pa0 = *(const bf16x8*)&sP[wv][lane & 15][(lane >> 4) * 8];
        bf16x8 pa1 = *(const bf16x8*)&sP[wv][lane & 15][32 + (lane >> 4) * 8];
        #pragma unroll
        for (int nf = 0; nf < 4; ++nf) {
            bf16x8 vb0 = *(const bf16x8*)&sVT[nf * 16 + (lane & 15)][(lane >> 4) * 8];
            o[nf] = __builtin_amdgcn_mfma_f32_16x16x32_bf16(pa0, vb0, o[nf], 0, 0, 0);
            bf16x8 vb1 = *(const bf16x8*)&sVT[nf * 16 + (lane & 15)][32 + (lane >> 4) * 8];
            o[nf] = __builtin_amdgcn_mfma_f32_16x16x32_bf16(pa1, vb1, o[nf], 0, 0, 0);
        }
    }

    // deferred l reduce (row spread over 16 lanes of same group)
    float inv[4];
    #pragma unroll
    for (int r = 0; r < 4; ++r) {
        float l = lsum[r];
        #pragma unroll
        for (int off = 1; off < 16; off <<= 1)
            l += __shfl_xor(l, off, 16);
        inv[r] = 1.0f / l;
    }

    #pragma unroll
    for (int nf = 0; nf < 4; ++nf) {
        int col = h * HD + nf * 16 + (lane & 15);
        #pragma unroll
        for (int r = 0; r < 4; ++r) {
            int rowg = qt * 64 + wv * 16 + (lane >> 4) * 4 + r;
            ctxb[((size_t)b * T_ + rowg) * NS + col] = f2bf(o[nf][r] * inv[r]);
        }
    }
}

// ---------------- kernel 3: out-projection (ctx bf16 in ws -> d_out) ------
// A-tile staged once; B register-direct from L2-hot Wo; no barriers in K-loop.
// XCD-affinity swizzle: logical block L=(g&7)*112+(g>>3) puts batch b=L/7 on
// XCD b/16 -- the same XCD whose attn blocks wrote those ctx rows (partial
// L2 reuse of the 5.5 MB/XCD ctx slice).
__global__ __launch_bounds__(256) void k_oproj(
    const unsigned short* __restrict__ ws, const float* __restrict__ bo,
    float* __restrict__ out)
{
    const int L = (blockIdx.x & 7) * 112 + (blockIdx.x >> 3);
    const int m0 = L * 64;
    const int tid = threadIdx.x;
    const int lane = tid & 63, wv = tid >> 6;

    __shared__ __align__(16) unsigned short sA[64][392];

    const unsigned short* ctxb = ws + OFF_CTX;

    {   // stage 64x384 ctx rows (bf16, straight copy)
        int r = tid >> 2, seg = tid & 3;
        const unsigned short* src = ctxb + (size_t)(m0 + r) * NS + seg * 96;
        unsigned short* dst = &sA[r][seg * 96];
        #pragma unroll
        for (int j = 0; j < 12; ++j)
            *(short8v*)(dst + j * 8) = *(const short8v*)(src + j * 8);
    }
    __syncthreads();

    f32x4 acc[4][6];
    #pragma unroll
    for (int i = 0; i < 4; ++i)
        #pragma unroll
        for (int j = 0; j < 6; ++j) acc[i][j] = (f32x4){0.f, 0.f, 0.f, 0.f};

    const int colA = lane & 15;
    const int kb = (lane >> 4) * 8;
    const unsigned short* wlane =
        ws + OFF_WO + (size_t)(wv * 96 + colA) * NS + kb;

    #pragma unroll 2
    for (int kc = 0; kc < 12; ++kc) {
        bf16x8 a[4], bfr[6];
        #pragma unroll
        for (int mf = 0; mf < 4; ++mf)
            a[mf] = *(const bf16x8*)&sA[mf * 16 + colA][kc * 32 + kb];
        #pragma unroll
        for (int nf = 0; nf < 6; ++nf)
            bfr[nf] = *(const bf16x8*)(wlane + (size_t)(nf * 16) * NS + kc * 32);
        #pragma unroll
        for (int mf = 0; mf < 4; ++mf)
            #pragma unroll
            for (int nf = 0; nf < 6; ++nf)
                acc[mf][nf] = __builtin_amdgcn_mfma_f32_16x16x32_bf16(
                    a[mf], bfr[nf], acc[mf][nf], 0, 0, 0);
    }

    const int r0 = (lane >> 4) * 4;
    #pragma unroll
    for (int nf = 0; nf < 6; ++nf) {
        int n = wv * 96 + nf * 16 + colA;
        float bias = bo[n];
        #pragma unroll
        for (int mf = 0; mf < 4; ++mf)
            #pragma unroll
            for (int r = 0; r < 4; ++r)
                out[(size_t)(m0 + mf * 16 + r0 + r) * NS + n] = acc[mf][nf][r] + bias;
    }
}

extern "C" void kernel_launch(void* const* d_in, const int* in_sizes, int n_in,
                              void* d_out, int out_size, void* d_ws, size_t ws_size,
                              hipStream_t stream) {
    const int*   x   = (const int*)d_in[0];
    const float* emb = (const float*)d_in[1];
    const float* Wq  = (const float*)d_in[2];
    const float* bq  = (const float*)d_in[3];
    const float* Wk  = (const float*)d_in[4];
    const float* Wv  = (const float*)d_in[5];
    const float* bv  = (const float*)d_in[6];
    const float* Wo  = (const float*)d_in[7];
    const float* bo  = (const float*)d_in[8];

    float* out   = (float*)d_out;
    float* out_k = out + NOUT;
    float* out_v = out + 2 * (size_t)NOUT;
    unsigned short* ws = (unsigned short*)d_ws;

    k_prep<<<dim3(144, 4), 256, 0, stream>>>(Wq, Wk, Wv, Wo, ws);
    k_table<<<dim3(313, 3), 256, 0, stream>>>(emb, ws, bq, bv, ws);
    k_attn_gather<<<dim3(NFUSE), 256, 0, stream>>>(x, ws, ws + OFF_CTX,
                                                   out_k, out_v);
    k_oproj<<<dim3(896), 256, 0, stream>>>(ws, bo, out);
}

// Round 16
// 189.238 us; speedup vs baseline: 1.1166x; 1.1166x over previous
//
#include <hip/hip_runtime.h>
#include <hip/hip_bf16.h>
#include <stdint.h>

typedef __bf16 bf16x8 __attribute__((ext_vector_type(8)));
typedef short short8v __attribute__((ext_vector_type(8)));
typedef float f32x4 __attribute__((ext_vector_type(4)));

#define B_     128
#define T_     448
#define NS     384
#define NH     6
#define HD     64
#define VOCAB_ 10000
#define NOUT   22020096   // B_*T_*NS

// ws layout (ushort element offsets). Tables are bf16.
// qtab: (emb@Wq^T + bq) * scale * log2(e)  (pre-scaled for exp2 softmax)
// ktab: (emb@Wk^T) * scale        (pre-scaled; gather multiplies by 1/scale)
// vtab: (emb@Wv^T + bv)           (unscaled)
// ctx : attention output, bf16 [M][384]
#define OFF_WQ   0
#define OFF_WK   147456
#define OFF_WV   294912
#define OFF_WO   442368
#define OFF_QTAB 589824
#define OFF_KTAB 4429824
#define OFF_VTAB 8269824
#define OFF_CTX  12109824
// end: 34129920 ushorts = 68.3 MB

#define NATT (B_ * NH * 7)        // 5376 attention blocks
#define NGAT 10752                // gather blocks (2752512 chunks / 256)
#define NFUSE (NATT * 3)          // 16128 fused-grid blocks (div by 8)

__device__ __forceinline__ unsigned short f2bf(float f) {
    // native f32->bf16 convert (RTNE on gfx950)
    union { __bf16 h; unsigned short u; } v;
    v.h = (__bf16)f;
    return v.u;
}
__device__ __forceinline__ float bf2f(unsigned short u) {
    union { uint32_t u; float f; } v; v.u = (uint32_t)u << 16;
    return v.f;
}

// ---------------- kernel 0: f32 -> bf16 weights only ----------------------
__global__ __launch_bounds__(256) void k_prep(
    const float* __restrict__ Wq, const float* __restrict__ Wk,
    const float* __restrict__ Wv, const float* __restrict__ Wo,
    unsigned short* __restrict__ ws)
{
    const float* srcs[4] = {Wq, Wk, Wv, Wo};
    const int seg = blockIdx.y;
    int i = (blockIdx.x * 256 + threadIdx.x) * 4;
    if (i >= 147456) return;
    float4 v = *(const float4*)(srcs[seg] + i);
    ushort4 o;
    o.x = f2bf(v.x); o.y = f2bf(v.y); o.z = f2bf(v.z); o.w = f2bf(v.w);
    *(ushort4*)(ws + seg * 147456 + i) = o;
}

// ---------------- kernel 1: vocab projection tables -----------------------
// grid (313, 3): 32 vocab rows per block; y: 0=q,1=k,2=v.
__global__ __launch_bounds__(256) void k_table(
    const float* __restrict__ emb, const unsigned short* __restrict__ ws,
    const float* __restrict__ bq, const float* __restrict__ bv,
    unsigned short* __restrict__ wso)
{
    const int p  = blockIdx.y;
    const int v0 = blockIdx.x * 32;
    const int tid = threadIdx.x;
    const int lane = tid & 63, wv = tid >> 6;

    __shared__ __align__(16) unsigned short sA[32][392];

    {   // stage 32x384 emb rows, f32 -> bf16
        int r = tid >> 3;
        int srow = min(v0 + r, VOCAB_ - 1);
        const float* src = emb + (size_t)srow * NS + (tid & 7) * 48;
        unsigned short* dst = &sA[r][(tid & 7) * 48];
        #pragma unroll
        for (int j = 0; j < 6; ++j) {
            float4 a0 = *(const float4*)(src + j * 8);
            float4 a1 = *(const float4*)(src + j * 8 + 4);
            ushort4 o0, o1;
            o0.x = f2bf(a0.x); o0.y = f2bf(a0.y); o0.z = f2bf(a0.z); o0.w = f2bf(a0.w);
            o1.x = f2bf(a1.x); o1.y = f2bf(a1.y); o1.z = f2bf(a1.z); o1.w = f2bf(a1.w);
            *(ushort4*)(dst + j * 8) = o0;
            *(ushort4*)(dst + j * 8 + 4) = o1;
        }
    }
    __syncthreads();

    f32x4 acc[2][6];
    #pragma unroll
    for (int i = 0; i < 2; ++i)
        #pragma unroll
        for (int j = 0; j < 6; ++j) acc[i][j] = (f32x4){0.f, 0.f, 0.f, 0.f};

    const int colA = lane & 15;
    const int kb = (lane >> 4) * 8;
    const unsigned short* wlane =
        ws + (size_t)p * 147456 + (size_t)(wv * 96 + colA) * NS + kb;

    #pragma unroll 2
    for (int kc = 0; kc < 12; ++kc) {
        bf16x8 a[2], b[6];
        #pragma unroll
        for (int mf = 0; mf < 2; ++mf)
            a[mf] = *(const bf16x8*)&sA[mf * 16 + colA][kc * 32 + kb];
        #pragma unroll
        for (int nf = 0; nf < 6; ++nf)
            b[nf] = *(const bf16x8*)(wlane + (size_t)(nf * 16) * NS + kc * 32);
        #pragma unroll
        for (int mf = 0; mf < 2; ++mf)
            #pragma unroll
            for (int nf = 0; nf < 6; ++nf)
                acc[mf][nf] = __builtin_amdgcn_mfma_f32_16x16x32_bf16(
                    a[mf], b[nf], acc[mf][nf], 0, 0, 0);
    }

    const int r0 = (lane >> 4) * 4;
    const float scale = 0.35355339059327373f;            // 64^-0.25
    const float qscale = 0.35355339059327373f * 1.4426950408889634f; // * log2(e)

    if (p == 0) {
        unsigned short* qt_ = wso + OFF_QTAB;
        #pragma unroll
        for (int nf = 0; nf < 6; ++nf) {
            int n = wv * 96 + nf * 16 + colA;
            float bias = bq[n];
            #pragma unroll
            for (int mf = 0; mf < 2; ++mf)
                #pragma unroll
                for (int r = 0; r < 4; ++r) {
                    int row = v0 + mf * 16 + r0 + r;
                    if (row < VOCAB_)
                        qt_[(size_t)row * NS + n] = f2bf((acc[mf][nf][r] + bias) * qscale);
                }
        }
    } else if (p == 1) {
        unsigned short* kt_ = wso + OFF_KTAB;
        #pragma unroll
        for (int nf = 0; nf < 6; ++nf) {
            int n = wv * 96 + nf * 16 + colA;
            #pragma unroll
            for (int mf = 0; mf < 2; ++mf)
                #pragma unroll
                for (int r = 0; r < 4; ++r) {
                    int row = v0 + mf * 16 + r0 + r;
                    if (row < VOCAB_)
                        kt_[(size_t)row * NS + n] = f2bf(acc[mf][nf][r] * scale);
                }
        }
    } else {
        unsigned short* vt_ = wso + OFF_VTAB;
        #pragma unroll
        for (int nf = 0; nf < 6; ++nf) {
            int n = wv * 96 + nf * 16 + colA;
            float bias = bv[n];
            #pragma unroll
            for (int mf = 0; mf < 2; ++mf)
                #pragma unroll
                for (int r = 0; r < 4; ++r) {
                    int row = v0 + mf * 16 + r0 + r;
                    if (row < VOCAB_)
                        vt_[(size_t)row * NS + n] = f2bf(acc[mf][nf][r] + bias);
                }
        }
    }
}

// ---------------- kernel 2: fused causal flash attention + k/v gather -----
// Round-6 structure (best measured: 192.9 us). Single change: gather's f32
// output writes use NON-TEMPORAL stores (nt flag) so the 176 MB write stream
// does not evict the 23 MB K/V tables from the per-XCD L2s. Attention's
// random table reads then stay L2-resident (round-7 FETCH=4.4x table size
// was the eviction signature; latency-hiding variants all failed because
// the latency was ~900cy HBM, not ~200cy L2).
__global__ __launch_bounds__(256) void k_attn_gather(
    const int* __restrict__ x, const unsigned short* __restrict__ ws,
    unsigned short* __restrict__ ctxb,
    float* __restrict__ out_k, float* __restrict__ out_v)
{
    const int swz = (blockIdx.x & 7) * (NFUSE / 8) + (blockIdx.x >> 3);
    const int r3 = swz % 3;
    const int q3 = swz / 3;

    if (r3 != 0) {
        // ---------------- gather path (2 of every 3 blocks) ----------------
        int i = (2 * q3 + (r3 - 1)) * 256 + threadIdx.x;  // chunk id < 2752512
        int row = i / 48;
        int c = (i - row * 48) * 8;
        int tok = x[row];
        const unsigned short* ks = ws + OFF_KTAB + (size_t)tok * NS + c;
        const unsigned short* vs = ws + OFF_VTAB + (size_t)tok * NS + c;
        ushort4 k0 = *(const ushort4*)ks;
        ushort4 k1 = *(const ushort4*)(ks + 4);
        ushort4 v0 = *(const ushort4*)vs;
        ushort4 v1 = *(const ushort4*)(vs + 4);
        const float inv = 2.8284271247461903f;   // 1/scale: ktab is pre-scaled
        f32x4 fk0 = {bf2f(k0.x) * inv, bf2f(k0.y) * inv, bf2f(k0.z) * inv, bf2f(k0.w) * inv};
        f32x4 fk1 = {bf2f(k1.x) * inv, bf2f(k1.y) * inv, bf2f(k1.z) * inv, bf2f(k1.w) * inv};
        f32x4 fv0 = {bf2f(v0.x), bf2f(v0.y), bf2f(v0.z), bf2f(v0.w)};
        f32x4 fv1 = {bf2f(v1.x), bf2f(v1.y), bf2f(v1.z), bf2f(v1.w)};
        size_t base = (size_t)row * NS + c;
        __builtin_nontemporal_store(fk0, (f32x4*)(out_k + base));
        __builtin_nontemporal_store(fk1, (f32x4*)(out_k + base + 4));
        __builtin_nontemporal_store(fv0, (f32x4*)(out_v + base));
        __builtin_nontemporal_store(fv1, (f32x4*)(out_v + base + 4));
        return;
    }

    // ---------------- attention path ----------------
    const int bid = q3;
    const int qt = bid % 7;
    const int h  = (bid / 7) % NH;
    const int b  = bid / (7 * NH);
    const int tid = threadIdx.x;
    const int lane = tid & 63, wv = tid >> 6;

    __shared__ __align__(16) unsigned short sK[64][72];
    __shared__ __align__(16) unsigned short sVT[64][72];
    __shared__ __align__(16) unsigned short sP[4][16][72];

    const int* xb = x + (size_t)b * T_;
    const unsigned short* qtab = ws + OFF_QTAB;
    const unsigned short* ktab = ws + OFF_KTAB;
    const unsigned short* vtab = ws + OFF_VTAB;

    const int qrow = qt * 64 + wv * 16 + (lane & 15);
    const int qtok = xb[qrow];
    const unsigned short* qbase =
        qtab + (size_t)qtok * NS + h * HD + (lane >> 4) * 8;
    bf16x8 qf0 = *(const bf16x8*)qbase;
    bf16x8 qf1 = *(const bf16x8*)(qbase + 32);

    f32x4 o[4];
    #pragma unroll
    for (int nf = 0; nf < 4; ++nf) o[nf] = (f32x4){0.f, 0.f, 0.f, 0.f};
    float lsum[4] = {0.f, 0.f, 0.f, 0.f};

    const int tk = tid >> 2;          // K-staging: token 0..63
    const int cc = (tid & 3) * 16;    // K-staging: d chunk
    const int vd = tid & 63;          // V-staging: d row
    const int vg = tid >> 6;          // V-staging: token group (16 tokens)

    // prefetch tile 0 into registers
    short8v kr0, kr1;
    unsigned short tv[16];
    {
        int tkn = xb[tk];
        const unsigned short* kset = ktab + (size_t)tkn * NS + h * HD + cc;
        kr0 = *(const short8v*)kset;
        kr1 = *(const short8v*)(kset + 8);
        #pragma unroll
        for (int j = 0; j < 16; ++j) {
            int t = xb[vg * 16 + j];
            tv[j] = vtab[(size_t)t * NS + h * HD + vd];
        }
    }

    for (int kv = 0; kv <= qt; ++kv) {
        __syncthreads();
        // write prefetched tile into LDS
        *(short8v*)&sK[tk][cc]           = kr0;
        *(short8v*)&sK[tk][cc + 8]       = kr1;
        *(short8v*)&sVT[vd][vg * 16]     = *(const short8v*)&tv[0];
        *(short8v*)&sVT[vd][vg * 16 + 8] = *(const short8v*)&tv[8];
        __syncthreads();

        // issue NEXT tile's loads now (after the barrier, so the compiler's
        // vmcnt(0)-before-s_barrier doesn't drain them): latency hides under
        // this tile's MFMA + exp work.
        if (kv < qt) {
            int base = (kv + 1) * 64;
            int tkn = xb[base + tk];
            const unsigned short* kset = ktab + (size_t)tkn * NS + h * HD + cc;
            kr0 = *(const short8v*)kset;
            kr1 = *(const short8v*)(kset + 8);
            #pragma unroll
            for (int j = 0; j < 16; ++j) {
                int t = xb[base + vg * 16 + j];
                tv[j] = vtab[(size_t)t * NS + h * HD + vd];
            }
        }

        // S = Q K^T  (16 q-rows x 64 kv-cols per wave); logits already *log2e
        f32x4 s[4];
        #pragma unroll
        for (int nf = 0; nf < 4; ++nf) s[nf] = (f32x4){0.f, 0.f, 0.f, 0.f};
        #pragma unroll
        for (int nf = 0; nf < 4; ++nf) {
            bf16x8 kb0 = *(const bf16x8*)&sK[nf * 16 + (lane & 15)][(lane >> 4) * 8];
            s[nf] = __builtin_amdgcn_mfma_f32_16x16x32_bf16(qf0, kb0, s[nf], 0, 0, 0);
            bf16x8 kb1 = *(const bf16x8*)&sK[nf * 16 + (lane & 15)][32 + (lane >> 4) * 8];
            s[nf] = __builtin_amdgcn_mfma_f32_16x16x32_bf16(qf1, kb1, s[nf], 0, 0, 0);
        }

        // no-max softmax: p = exp2(s); only diagonal tile needs the mask.
        // Tile-local row of this lane's r-th acc row is wv*16 + (lane>>4)*4 + r.
        if (kv == qt) {
            const int rloc = wv * 16 + (lane >> 4) * 4;   // tile-local row base
            const int cloc = lane & 15;
            #pragma unroll
            for (int nf = 0; nf < 4; ++nf)
                #pragma unroll
                for (int r = 0; r < 4; ++r) {
                    float sv = (cloc + nf * 16 > rloc + r) ? -1e30f : s[nf][r];
                    float p = exp2f(sv);
                    s[nf][r] = p;
                    lsum[r] += p;
                }
        } else {
            #pragma unroll
            for (int nf = 0; nf < 4; ++nf)
                #pragma unroll
                for (int r = 0; r < 4; ++r) {
                    float p = exp2f(s[nf][r]);
                    s[nf][r] = p;
                    lsum[r] += p;
                }
        }

        // P (D-layout) -> per-wave LDS -> A-frag layout
        #pragma unroll
        for (int nf = 0; nf < 4; ++nf)
            #pragma unroll
            for (int r = 0; r < 4; ++r)
                sP[wv][(lane >> 4) * 4 + r][nf * 16 + (lane & 15)] = f2bf(s[nf][r]);
        asm volatile("s_waitcnt lgkmcnt(0)" ::: "memory");

        bf16x8 pa0 = *(const bf16x8*)&sP[wv][lane & 15][(lane >> 4) * 8];
        bf16x8 pa1 = *(const bf16x8*)&sP[wv][lane & 15][32 + (lane >> 4) * 8];
        #pragma unroll
        for (int nf = 0; nf < 4; ++nf) {
            bf16x8 vb0 = *(const bf16x8*)&sVT[nf * 16 + (lane & 15)][(lane >> 4) * 8];
            o[nf] = __builtin_amdgcn_mfma_f32_16x16x32_bf16(pa0, vb0, o[nf], 0, 0, 0);
            bf16x8 vb1 = *(const bf16x8*)&sVT[nf * 16 + (lane & 15)][32 + (lane >> 4) * 8];
            o[nf] = __builtin_amdgcn_mfma_f32_16x16x32_bf16(pa1, vb1, o[nf], 0, 0, 0);
        }
    }

    // deferred l reduce (row spread over 16 lanes of same group)
    float inv[4];
    #pragma unroll
    for (int r = 0; r < 4; ++r) {
        float l = lsum[r];
        #pragma unroll
        for (int off = 1; off < 16; off <<= 1)
            l += __shfl_xor(l, off, 16);
        inv[r] = 1.0f / l;
    }

    #pragma unroll
    for (int nf = 0; nf < 4; ++nf) {
        int col = h * HD + nf * 16 + (lane & 15);
        #pragma unroll
        for (int r = 0; r < 4; ++r) {
            int rowg = qt * 64 + wv * 16 + (lane >> 4) * 4 + r;
            ctxb[((size_t)b * T_ + rowg) * NS + col] = f2bf(o[nf][r] * inv[r]);
        }
    }
}

// ---------------- kernel 3: out-projection (ctx bf16 in ws -> d_out) ------
// A-tile staged once; B register-direct from L2-hot Wo; no barriers in K-loop.
// Output writes non-temporal (never re-read; don't evict Wo/ctx from L2).
__global__ __launch_bounds__(256) void k_oproj(
    const unsigned short* __restrict__ ws, const float* __restrict__ bo,
    float* __restrict__ out)
{
    const int m0 = blockIdx.x * 64;
    const int tid = threadIdx.x;
    const int lane = tid & 63, wv = tid >> 6;

    __shared__ __align__(16) unsigned short sA[64][392];

    const unsigned short* ctxb = ws + OFF_CTX;

    {   // stage 64x384 ctx rows (bf16, straight copy)
        int r = tid >> 2, seg = tid & 3;
        const unsigned short* src = ctxb + (size_t)(m0 + r) * NS + seg * 96;
        unsigned short* dst = &sA[r][seg * 96];
        #pragma unroll
        for (int j = 0; j < 12; ++j)
            *(short8v*)(dst + j * 8) = *(const short8v*)(src + j * 8);
    }
    __syncthreads();

    f32x4 acc[4][6];
    #pragma unroll
    for (int i = 0; i < 4; ++i)
        #pragma unroll
        for (int j = 0; j < 6; ++j) acc[i][j] = (f32x4){0.f, 0.f, 0.f, 0.f};

    const int colA = lane & 15;
    const int kb = (lane >> 4) * 8;
    const unsigned short* wlane =
        ws + OFF_WO + (size_t)(wv * 96 + colA) * NS + kb;

    #pragma unroll 2
    for (int kc = 0; kc < 12; ++kc) {
        bf16x8 a[4], bfr[6];
        #pragma unroll
        for (int mf = 0; mf < 4; ++mf)
            a[mf] = *(const bf16x8*)&sA[mf * 16 + colA][kc * 32 + kb];
        #pragma unroll
        for (int nf = 0; nf < 6; ++nf)
            bfr[nf] = *(const bf16x8*)(wlane + (size_t)(nf * 16) * NS + kc * 32);
        #pragma unroll
        for (int mf = 0; mf < 4; ++mf)
            #pragma unroll
            for (int nf = 0; nf < 6; ++nf)
                acc[mf][nf] = __builtin_amdgcn_mfma_f32_16x16x32_bf16(
                    a[mf], bfr[nf], acc[mf][nf], 0, 0, 0);
    }

    const int r0 = (lane >> 4) * 4;
    #pragma unroll
    for (int nf = 0; nf < 6; ++nf) {
        int n = wv * 96 + nf * 16 + colA;
        float bias = bo[n];
        #pragma unroll
        for (int mf = 0; mf < 4; ++mf)
            #pragma unroll
            for (int r = 0; r < 4; ++r)
                __builtin_nontemporal_store(
                    acc[mf][nf][r] + bias,
                    &out[(size_t)(m0 + mf * 16 + r0 + r) * NS + n]);
    }
}

extern "C" void kernel_launch(void* const* d_in, const int* in_sizes, int n_in,
                              void* d_out, int out_size, void* d_ws, size_t ws_size,
                              hipStream_t stream) {
    const int*   x   = (const int*)d_in[0];
    const float* emb = (const float*)d_in[1];
    const float* Wq  = (const float*)d_in[2];
    const float* bq  = (const float*)d_in[3];
    const float* Wk  = (const float*)d_in[4];
    const float* Wv  = (const float*)d_in[5];
    const float* bv  = (const float*)d_in[6];
    const float* Wo  = (const float*)d_in[7];
    const float* bo  = (const float*)d_in[8];

    float* out   = (float*)d_out;
    float* out_k = out + NOUT;
    float* out_v = out + 2 * (size_t)NOUT;
    unsigned short* ws = (unsigned short*)d_ws;

    k_prep<<<dim3(144, 4), 256, 0, stream>>>(Wq, Wk, Wv, Wo, ws);
    k_table<<<dim3(313, 3), 256, 0, stream>>>(emb, ws, bq, bv, ws);
    k_attn_gather<<<dim3(NFUSE), 256, 0, stream>>>(x, ws, ws + OFF_CTX,
                                                   out_k, out_v);
    k_oproj<<<dim3(896), 256, 0, stream>>>(ws, bo, out);
}